// Round 8
// baseline (121.545 us; speedup 1.0000x reference)
//
#include <hip/hip_runtime.h>

#define THRESH 1.0f

typedef float fvec4 __attribute__((ext_vector_type(4)));

__device__ __forceinline__ float rl(float v, int l) {
    return __int_as_float(__builtin_amdgcn_readlane(__float_as_int(v), l));
}

// ---------- W transpose: Wt[k][m] = W[m][k] (into d_ws) ----------
__global__ __launch_bounds__(256) void transpose_kernel(
    const float* __restrict__ W, float* __restrict__ Wt, int M, int D)
{
    __shared__ float tile[32][33];
    const int tilesK = D / 32;
    const int bx = blockIdx.x % tilesK;   // k tile
    const int by = blockIdx.x / tilesK;   // m tile
    const int lx = threadIdx.x & 31;
    const int ly = threadIdx.x >> 5;      // 0..7
    #pragma unroll
    for (int j = 0; j < 4; ++j)
        tile[ly + j * 8][lx] = W[(size_t)(by * 32 + ly + j * 8) * D + bx * 32 + lx];
    __syncthreads();
    #pragma unroll
    for (int j = 0; j < 4; ++j)
        Wt[(size_t)(bx * 32 + ly + j * 8) * M + by * 32 + lx] = tile[lx][ly + j * 8];
}

// ---------- row kernel: one block per batch row, grid=B (4 blocks/CU) ----------
// Thread = (q = m-quarter, p = position). Counts in registers, 4-way LDS combine.
// Phase-staggered prologue: half the blocks stream 32 m-steps before computing
// scores so HBM never idles during the L2-bound prologue window.
__global__ __launch_bounds__(256) void row_kernel(
    const float* __restrict__ x, const float* __restrict__ mem,
    const float* __restrict__ Wt, const float* __restrict__ bias,
    float* __restrict__ mem_new, float* __restrict__ scores,
    float* __restrict__ mixed, int plane4)
{
    const int b    = blockIdx.x;
    const int tid  = threadIdx.x;
    const int wave = tid >> 6;
    const int lane = tid & 63;
    const int q    = wave;               // m-quarter
    const int p    = lane;               // fvec4 position within row
    const int pos4 = b * 64 + p;

    __shared__ __align__(16) float sc_f[256];
    __shared__ fvec4 cnt_lds[4][64];
    __shared__ float wredm[4];
    __shared__ float wreds[4];

    const fvec4* mem4 = reinterpret_cast<const fvec4*>(mem);
    fvec4* out4       = reinterpret_cast<fvec4*>(mem_new);
    const fvec4 xv    = reinterpret_cast<const fvec4*>(x)[pos4];

    float cx = 0.f, cy = 0.f, cz = 0.f, cw = 0.f;

    // R3/R7-proven bit-exact neuron step
    auto step = [&](int m) {
        const float bm = (float)m;
        const size_t off = (size_t)m * plane4 + pos4;
        const fvec4 mv = __builtin_nontemporal_load(&mem4[off]);
        fvec4 nv;
        nv.x = __fsub_rn(__fadd_rn(__fmul_rn(bm, mv.x), xv.x),
                         (mv.x - THRESH > 0.f) ? THRESH : 0.f);
        nv.y = __fsub_rn(__fadd_rn(__fmul_rn(bm, mv.y), xv.y),
                         (mv.y - THRESH > 0.f) ? THRESH : 0.f);
        nv.z = __fsub_rn(__fadd_rn(__fmul_rn(bm, mv.z), xv.z),
                         (mv.z - THRESH > 0.f) ? THRESH : 0.f);
        nv.w = __fsub_rn(__fadd_rn(__fmul_rn(bm, mv.w), xv.w),
                         (mv.w - THRESH > 0.f) ? THRESH : 0.f);
        __builtin_nontemporal_store(nv, &out4[off]);
        cx += (nv.x - THRESH > 0.f) ? 1.f : 0.f;
        cy += (nv.y - THRESH > 0.f) ? 1.f : 0.f;
        cz += (nv.z - THRESH > 0.f) ? 1.f : 0.f;
        cw += (nv.w - THRESH > 0.f) ? 1.f : 0.f;
    };

    // scores for row b: thread tid owns logit m=tid (coalesced Wt columns,
    // x broadcast via v_readlane). Contains 2 block-uniform barriers.
    auto prologue = [&]() {
        const fvec4 xq = reinterpret_cast<const fvec4*>(x)[(size_t)b * 64 + lane];
        float a0 = 0.f;
        #pragma unroll 4
        for (int j = 0; j < 64; ++j) {
            const float w0 = Wt[(size_t)(4 * j + 0) * 256 + tid];
            const float w1 = Wt[(size_t)(4 * j + 1) * 256 + tid];
            const float w2 = Wt[(size_t)(4 * j + 2) * 256 + tid];
            const float w3 = Wt[(size_t)(4 * j + 3) * 256 + tid];
            a0 = fmaf(w0, rl(xq.x, j), a0);
            a0 = fmaf(w1, rl(xq.y, j), a0);
            a0 = fmaf(w2, rl(xq.z, j), a0);
            a0 = fmaf(w3, rl(xq.w, j), a0);
        }
        const float l = a0 + bias[tid];

        float mx = l;
        #pragma unroll
        for (int off = 32; off; off >>= 1) mx = fmaxf(mx, __shfl_xor(mx, off, 64));
        if (lane == 0) wredm[wave] = mx;
        __syncthreads();
        mx = fmaxf(fmaxf(wredm[0], wredm[1]), fmaxf(wredm[2], wredm[3]));

        const float e = expf(l - mx);
        float s = e;
        #pragma unroll
        for (int off = 32; off; off >>= 1) s += __shfl_xor(s, off, 64);
        if (lane == 0) wreds[wave] = s;
        __syncthreads();
        const float tot = wreds[0] + wreds[1] + wreds[2] + wreds[3];

        const float sc = e / tot;
        sc_f[tid] = sc;
        scores[(size_t)b * 256 + tid] = sc;
    };

    const int mstart = q * 64;

    if (((blockIdx.x >> 3) & 1) == 0) {
        // stream-first: cover HBM while other blocks run their prologue
        #pragma unroll 8
        for (int m = mstart; m < mstart + 32; ++m) step(m);
        prologue();
        #pragma unroll 8
        for (int m = mstart + 32; m < mstart + 64; ++m) step(m);
    } else {
        prologue();
        #pragma unroll 8
        for (int m = mstart; m < mstart + 64; ++m) step(m);
    }

    fvec4 cv; cv.x = cx; cv.y = cy; cv.z = cz; cv.w = cw;
    cnt_lds[q][p] = cv;
    __syncthreads();

    // epilogue: mixed[b, 4p..4p+3] = scores[b, 4p..4p+3] * total spike count
    if (q == 0) {
        const fvec4 c0 = cnt_lds[0][p];
        const fvec4 c1 = cnt_lds[1][p];
        const fvec4 c2 = cnt_lds[2][p];
        const fvec4 c3 = cnt_lds[3][p];
        fvec4 c;
        c.x = (c0.x + c1.x) + (c2.x + c3.x);
        c.y = (c0.y + c1.y) + (c2.y + c3.y);
        c.z = (c0.z + c1.z) + (c2.z + c3.z);
        c.w = (c0.w + c1.w) + (c2.w + c3.w);
        const fvec4 sc = reinterpret_cast<const fvec4*>(sc_f)[p];
        fvec4 r;
        r.x = sc.x * c.x; r.y = sc.y * c.y;
        r.z = sc.z * c.z; r.w = sc.w * c.w;
        reinterpret_cast<fvec4*>(mixed)[pos4] = r;
    }
}

// ---------- fallback kernels (used if ws too small / odd shapes) ----------
__global__ __launch_bounds__(256) void scores_kernel_fb(
    const float* __restrict__ x, const float* __restrict__ W,
    const float* __restrict__ bias, float* __restrict__ scores,
    int D, int M)
{
    const int b = blockIdx.x;
    __shared__ __align__(16) float x_lds[256];
    __shared__ float logits[256];
    __shared__ float wred[4];
    const int tid  = threadIdx.x;
    const int wave = tid >> 6;
    const int lane = tid & 63;
    x_lds[tid] = x[(size_t)b * D + tid];
    __syncthreads();
    const float4* W4 = reinterpret_cast<const float4*>(W);
    const float4  xv = reinterpret_cast<const float4*>(x_lds)[lane];
    for (int i = 0; i < 64; ++i) {
        const int m = wave * 64 + i;
        const float4 wv = W4[(size_t)m * 64 + lane];
        float pp = wv.x * xv.x + wv.y * xv.y + wv.z * xv.z + wv.w * xv.w;
        #pragma unroll
        for (int off = 32; off; off >>= 1) pp += __shfl_xor(pp, off, 64);
        if (lane == 0) logits[m] = pp + bias[m];
    }
    __syncthreads();
    float l = logits[tid];
    float mx = l;
    #pragma unroll
    for (int off = 32; off; off >>= 1) mx = fmaxf(mx, __shfl_xor(mx, off, 64));
    if (lane == 0) wred[wave] = mx;
    __syncthreads();
    mx = fmaxf(fmaxf(wred[0], wred[1]), fmaxf(wred[2], wred[3]));
    __syncthreads();
    const float e = expf(l - mx);
    float s = e;
    #pragma unroll
    for (int off = 32; off; off >>= 1) s += __shfl_xor(s, off, 64);
    if (lane == 0) wred[wave] = s;
    __syncthreads();
    const float tot = wred[0] + wred[1] + wred[2] + wred[3];
    scores[(size_t)b * M + tid] = e / tot;
}

__global__ __launch_bounds__(256) void neuron_kernel_fb(
    const float* __restrict__ x, const float* __restrict__ mem,
    const float* __restrict__ scores, float* __restrict__ mixed,
    float* __restrict__ mem_new, int M, int plane4)
{
    const int idx = blockIdx.x * 256 + threadIdx.x;
    if (idx >= plane4) return;
    const float4* x4   = reinterpret_cast<const float4*>(x);
    const float4* mem4 = reinterpret_cast<const float4*>(mem);
    const float4* sc4  = reinterpret_cast<const float4*>(scores);
    float4* out4       = reinterpret_cast<float4*>(mem_new);
    float4* mix4       = reinterpret_cast<float4*>(mixed);
    const float4 xv = x4[idx];
    float cx = 0.f, cy = 0.f, cz = 0.f, cw = 0.f;
    #pragma unroll 4
    for (int m = 0; m < M; ++m) {
        const float bm = (float)m;
        const size_t off = (size_t)m * plane4 + idx;
        const float4 mv = mem4[off];
        float4 nv;
        nv.x = __fsub_rn(__fadd_rn(__fmul_rn(bm, mv.x), xv.x),
                         (mv.x - THRESH > 0.f) ? THRESH : 0.f);
        nv.y = __fsub_rn(__fadd_rn(__fmul_rn(bm, mv.y), xv.y),
                         (mv.y - THRESH > 0.f) ? THRESH : 0.f);
        nv.z = __fsub_rn(__fadd_rn(__fmul_rn(bm, mv.z), xv.z),
                         (mv.z - THRESH > 0.f) ? THRESH : 0.f);
        nv.w = __fsub_rn(__fadd_rn(__fmul_rn(bm, mv.w), xv.w),
                         (mv.w - THRESH > 0.f) ? THRESH : 0.f);
        out4[off] = nv;
        cx += (nv.x - THRESH > 0.f) ? 1.f : 0.f;
        cy += (nv.y - THRESH > 0.f) ? 1.f : 0.f;
        cz += (nv.z - THRESH > 0.f) ? 1.f : 0.f;
        cw += (nv.w - THRESH > 0.f) ? 1.f : 0.f;
    }
    const float4 sc = sc4[idx];
    float4 mx;
    mx.x = sc.x * cx; mx.y = sc.y * cy; mx.z = sc.z * cz; mx.w = sc.w * cw;
    mix4[idx] = mx;
}

extern "C" void kernel_launch(void* const* d_in, const int* in_sizes, int n_in,
                              void* d_out, int out_size, void* d_ws, size_t ws_size,
                              hipStream_t stream) {
    const float* x    = (const float*)d_in[0];
    const float* mem  = (const float*)d_in[1];
    const float* W    = (const float*)d_in[2];
    const float* bias = (const float*)d_in[3];

    const int M = in_sizes[3];             // 256
    const int D = in_sizes[2] / M;         // 256
    const int B = in_sizes[0] / D;         // 1024
    const int plane  = B * D;              // 262144
    const int plane4 = plane / 4;          // 65536

    float* out_mixed  = (float*)d_out;                       // [B*D]
    float* out_mem    = out_mixed + plane;                   // [M*B*D]
    float* out_scores = out_mem + (size_t)M * plane;         // [B*M]

    const size_t wt_bytes = (size_t)M * D * sizeof(float);   // 256 KB

    const bool shapes_ok = (D == 256) && (M == 256);

    if (shapes_ok && ws_size >= wt_bytes) {
        float* Wt = (float*)d_ws;
        transpose_kernel<<<(M / 32) * (D / 32), 256, 0, stream>>>(W, Wt, M, D);
        row_kernel<<<B, 256, 0, stream>>>(
            x, mem, Wt, bias, out_mem, out_scores, out_mixed, plane4);
    } else {
        scores_kernel_fb<<<B, 256, 0, stream>>>(x, W, bias, out_scores, D, M);
        neuron_kernel_fb<<<(plane4 + 255) / 256, 256, 0, stream>>>(
            x, mem, out_scores, out_mixed, out_mem, M, plane4);
    }
}

// Round 9
// 109.090 us; speedup vs baseline: 1.1142x; 1.1142x over previous
//
#include <hip/hip_runtime.h>

#define THRESH 1.0f

typedef float fvec4 __attribute__((ext_vector_type(4)));

__device__ __forceinline__ float rl(float v, int l) {
    return __int_as_float(__builtin_amdgcn_readlane(__float_as_int(v), l));
}

// ---------- W transpose: Wt[k][m] = W[m][k] (into d_ws) ----------
__global__ __launch_bounds__(256) void transpose_kernel(
    const float* __restrict__ W, float* __restrict__ Wt, int M, int D)
{
    __shared__ float tile[32][33];
    const int tilesK = D / 32;
    const int bx = blockIdx.x % tilesK;   // k tile
    const int by = blockIdx.x / tilesK;   // m tile
    const int lx = threadIdx.x & 31;
    const int ly = threadIdx.x >> 5;      // 0..7
    #pragma unroll
    for (int j = 0; j < 4; ++j)
        tile[ly + j * 8][lx] = W[(size_t)(by * 32 + ly + j * 8) * D + bx * 32 + lx];
    __syncthreads();
    #pragma unroll
    for (int j = 0; j < 4; ++j)
        Wt[(size_t)(bx * 32 + ly + j * 8) * M + by * 32 + lx] = tile[lx][ly + j * 8];
}

// ---------- row-pair kernel, 512 threads: rows (b0, b0+1) ----------
// Prologue: waves 0-3 compute row b0's 256 logits (thread htid owns logit
//   m=htid), waves 4-7 row b1's — same logit partition as R7, bit-identical.
// Stream: thread = (q = m-quarter, pp = panel position 0..127), 64 m-steps,
//   counts in registers; 4-deep register prefetch issued BEFORE the prologue
//   keeps HBM busy during the L2-bound prologue window.
// 512 blocks x 8 waves, 2 blocks/CU => 16 waves/CU for the stream phase.
__global__ __launch_bounds__(512, 4) void rowpair512_kernel(
    const float* __restrict__ x, const float* __restrict__ mem,
    const float* __restrict__ Wt, const float* __restrict__ bias,
    float* __restrict__ mem_new, float* __restrict__ scores,
    float* __restrict__ mixed, int plane4)
{
    const int b0   = blockIdx.x * 2;
    const int tid  = threadIdx.x;
    const int lane = tid & 63;
    const int half = tid >> 8;            // prologue row (0/1)
    const int htid = tid & 255;           // logit index within row
    const int w4   = (tid >> 6) & 3;      // wave within half

    const int q    = tid >> 7;            // stream m-quarter 0..3
    const int pp   = tid & 127;           // position in 2-row panel
    const int pos4 = b0 * 64 + pp;        // fvec4 index in [B,D] plane

    __shared__ __align__(16) float sc_lds[2][256];
    __shared__ fvec4 cnt_lds[4][128];
    __shared__ float wredm[2][4];
    __shared__ float wreds[2][4];

    const fvec4* mem4 = reinterpret_cast<const fvec4*>(mem);
    fvec4* out4       = reinterpret_cast<fvec4*>(mem_new);

    // ---- prefetch first 4 stream loads (fills HBM pipe under prologue) ----
    const int mstart = q * 64;
    const fvec4 pf0 = __builtin_nontemporal_load(&mem4[(size_t)(mstart + 0) * plane4 + pos4]);
    const fvec4 pf1 = __builtin_nontemporal_load(&mem4[(size_t)(mstart + 1) * plane4 + pos4]);
    const fvec4 pf2 = __builtin_nontemporal_load(&mem4[(size_t)(mstart + 2) * plane4 + pos4]);
    const fvec4 pf3 = __builtin_nontemporal_load(&mem4[(size_t)(mstart + 3) * plane4 + pos4]);

    // ---- prologue: scores for row (b0+half) ----
    {
        const fvec4 xq = reinterpret_cast<const fvec4*>(x)[(size_t)(b0 + half) * 64 + lane];
        float a0 = 0.f;
        #pragma unroll 4
        for (int j = 0; j < 64; ++j) {
            const float w0 = Wt[(size_t)(4 * j + 0) * 256 + htid];
            const float w1 = Wt[(size_t)(4 * j + 1) * 256 + htid];
            const float w2 = Wt[(size_t)(4 * j + 2) * 256 + htid];
            const float w3 = Wt[(size_t)(4 * j + 3) * 256 + htid];
            a0 = fmaf(w0, rl(xq.x, j), a0);
            a0 = fmaf(w1, rl(xq.y, j), a0);
            a0 = fmaf(w2, rl(xq.z, j), a0);
            a0 = fmaf(w3, rl(xq.w, j), a0);
        }
        const float l = a0 + bias[htid];

        float mx = l;
        #pragma unroll
        for (int off = 32; off; off >>= 1) mx = fmaxf(mx, __shfl_xor(mx, off, 64));
        if (lane == 0) wredm[half][w4] = mx;
        __syncthreads();
        mx = fmaxf(fmaxf(wredm[half][0], wredm[half][1]),
                   fmaxf(wredm[half][2], wredm[half][3]));

        const float e = expf(l - mx);
        float s = e;
        #pragma unroll
        for (int off = 32; off; off >>= 1) s += __shfl_xor(s, off, 64);
        if (lane == 0) wreds[half][w4] = s;
        __syncthreads();
        const float tot = wreds[half][0] + wreds[half][1] +
                          wreds[half][2] + wreds[half][3];

        const float sc = e / tot;
        sc_lds[half][htid] = sc;
        scores[(size_t)(b0 + half) * 256 + htid] = sc;
    }

    // ---- stream: m in [mstart, mstart+64), bit-exact neuron math ----
    const fvec4 xv = reinterpret_cast<const fvec4*>(x)[pos4];   // L1/L2 hot
    float cx = 0.f, cy = 0.f, cz = 0.f, cw = 0.f;

    auto process = [&](const fvec4 mv, int m) {
        const float bm = (float)m;
        const size_t off = (size_t)m * plane4 + pos4;
        fvec4 nv;
        nv.x = __fsub_rn(__fadd_rn(__fmul_rn(bm, mv.x), xv.x),
                         (mv.x - THRESH > 0.f) ? THRESH : 0.f);
        nv.y = __fsub_rn(__fadd_rn(__fmul_rn(bm, mv.y), xv.y),
                         (mv.y - THRESH > 0.f) ? THRESH : 0.f);
        nv.z = __fsub_rn(__fadd_rn(__fmul_rn(bm, mv.z), xv.z),
                         (mv.z - THRESH > 0.f) ? THRESH : 0.f);
        nv.w = __fsub_rn(__fadd_rn(__fmul_rn(bm, mv.w), xv.w),
                         (mv.w - THRESH > 0.f) ? THRESH : 0.f);
        __builtin_nontemporal_store(nv, &out4[off]);
        cx += (nv.x - THRESH > 0.f) ? 1.f : 0.f;
        cy += (nv.y - THRESH > 0.f) ? 1.f : 0.f;
        cz += (nv.z - THRESH > 0.f) ? 1.f : 0.f;
        cw += (nv.w - THRESH > 0.f) ? 1.f : 0.f;
    };

    process(pf0, mstart + 0);
    process(pf1, mstart + 1);
    process(pf2, mstart + 2);
    process(pf3, mstart + 3);

    #pragma unroll 8
    for (int mm = 4; mm < 64; ++mm) {
        const int m = mstart + mm;
        const fvec4 mv = __builtin_nontemporal_load(&mem4[(size_t)m * plane4 + pos4]);
        process(mv, m);
    }

    fvec4 cv; cv.x = cx; cv.y = cy; cv.z = cz; cv.w = cw;
    cnt_lds[q][pp] = cv;
    __syncthreads();

    // ---- epilogue: mixed[pos] = scores_flat[pos] * total spike count ----
    if (q == 0) {
        const fvec4 c0 = cnt_lds[0][pp];
        const fvec4 c1 = cnt_lds[1][pp];
        const fvec4 c2 = cnt_lds[2][pp];
        const fvec4 c3 = cnt_lds[3][pp];
        fvec4 c;
        c.x = (c0.x + c1.x) + (c2.x + c3.x);
        c.y = (c0.y + c1.y) + (c2.y + c3.y);
        c.z = (c0.z + c1.z) + (c2.z + c3.z);
        c.w = (c0.w + c1.w) + (c2.w + c3.w);
        const fvec4 sc = reinterpret_cast<const fvec4*>(sc_lds[pp >> 6])[pp & 63];
        fvec4 r;
        r.x = sc.x * c.x; r.y = sc.y * c.y;
        r.z = sc.z * c.z; r.w = sc.w * c.w;
        reinterpret_cast<fvec4*>(mixed)[pos4] = r;
    }
}

// ---------- fallback kernels (used if ws too small / odd shapes) ----------
__global__ __launch_bounds__(256) void scores_kernel_fb(
    const float* __restrict__ x, const float* __restrict__ W,
    const float* __restrict__ bias, float* __restrict__ scores,
    int D, int M)
{
    const int b = blockIdx.x;
    __shared__ __align__(16) float x_lds[256];
    __shared__ float logits[256];
    __shared__ float wred[4];
    const int tid  = threadIdx.x;
    const int wave = tid >> 6;
    const int lane = tid & 63;
    x_lds[tid] = x[(size_t)b * D + tid];
    __syncthreads();
    const float4* W4 = reinterpret_cast<const float4*>(W);
    const float4  xv = reinterpret_cast<const float4*>(x_lds)[lane];
    for (int i = 0; i < 64; ++i) {
        const int m = wave * 64 + i;
        const float4 wv = W4[(size_t)m * 64 + lane];
        float pp = wv.x * xv.x + wv.y * xv.y + wv.z * xv.z + wv.w * xv.w;
        #pragma unroll
        for (int off = 32; off; off >>= 1) pp += __shfl_xor(pp, off, 64);
        if (lane == 0) logits[m] = pp + bias[m];
    }
    __syncthreads();
    float l = logits[tid];
    float mx = l;
    #pragma unroll
    for (int off = 32; off; off >>= 1) mx = fmaxf(mx, __shfl_xor(mx, off, 64));
    if (lane == 0) wred[wave] = mx;
    __syncthreads();
    mx = fmaxf(fmaxf(wred[0], wred[1]), fmaxf(wred[2], wred[3]));
    __syncthreads();
    const float e = expf(l - mx);
    float s = e;
    #pragma unroll
    for (int off = 32; off; off >>= 1) s += __shfl_xor(s, off, 64);
    if (lane == 0) wred[wave] = s;
    __syncthreads();
    const float tot = wred[0] + wred[1] + wred[2] + wred[3];
    scores[(size_t)b * M + tid] = e / tot;
}

__global__ __launch_bounds__(256) void neuron_kernel_fb(
    const float* __restrict__ x, const float* __restrict__ mem,
    const float* __restrict__ scores, float* __restrict__ mixed,
    float* __restrict__ mem_new, int M, int plane4)
{
    const int idx = blockIdx.x * 256 + threadIdx.x;
    if (idx >= plane4) return;
    const float4* x4   = reinterpret_cast<const float4*>(x);
    const float4* mem4 = reinterpret_cast<const float4*>(mem);
    const float4* sc4  = reinterpret_cast<const float4*>(scores);
    float4* out4       = reinterpret_cast<float4*>(mem_new);
    float4* mix4       = reinterpret_cast<float4*>(mixed);
    const float4 xv = x4[idx];
    float cx = 0.f, cy = 0.f, cz = 0.f, cw = 0.f;
    #pragma unroll 4
    for (int m = 0; m < M; ++m) {
        const float bm = (float)m;
        const size_t off = (size_t)m * plane4 + idx;
        const float4 mv = mem4[off];
        float4 nv;
        nv.x = __fsub_rn(__fadd_rn(__fmul_rn(bm, mv.x), xv.x),
                         (mv.x - THRESH > 0.f) ? THRESH : 0.f);
        nv.y = __fsub_rn(__fadd_rn(__fmul_rn(bm, mv.y), xv.y),
                         (mv.y - THRESH > 0.f) ? THRESH : 0.f);
        nv.z = __fsub_rn(__fadd_rn(__fmul_rn(bm, mv.z), xv.z),
                         (mv.z - THRESH > 0.f) ? THRESH : 0.f);
        nv.w = __fsub_rn(__fadd_rn(__fmul_rn(bm, mv.w), xv.w),
                         (mv.w - THRESH > 0.f) ? THRESH : 0.f);
        out4[off] = nv;
        cx += (nv.x - THRESH > 0.f) ? 1.f : 0.f;
        cy += (nv.y - THRESH > 0.f) ? 1.f : 0.f;
        cz += (nv.z - THRESH > 0.f) ? 1.f : 0.f;
        cw += (nv.w - THRESH > 0.f) ? 1.f : 0.f;
    }
    const float4 sc = sc4[idx];
    float4 mx;
    mx.x = sc.x * cx; mx.y = sc.y * cy; mx.z = sc.z * cz; mx.w = sc.w * cw;
    mix4[idx] = mx;
}

extern "C" void kernel_launch(void* const* d_in, const int* in_sizes, int n_in,
                              void* d_out, int out_size, void* d_ws, size_t ws_size,
                              hipStream_t stream) {
    const float* x    = (const float*)d_in[0];
    const float* mem  = (const float*)d_in[1];
    const float* W    = (const float*)d_in[2];
    const float* bias = (const float*)d_in[3];

    const int M = in_sizes[3];             // 256
    const int D = in_sizes[2] / M;         // 256
    const int B = in_sizes[0] / D;         // 1024
    const int plane  = B * D;              // 262144
    const int plane4 = plane / 4;          // 65536

    float* out_mixed  = (float*)d_out;                       // [B*D]
    float* out_mem    = out_mixed + plane;                   // [M*B*D]
    float* out_scores = out_mem + (size_t)M * plane;         // [B*M]

    const size_t wt_bytes = (size_t)M * D * sizeof(float);   // 256 KB

    const bool shapes_ok = (D == 256) && (M == 256) && (B % 2 == 0);

    if (shapes_ok && ws_size >= wt_bytes) {
        float* Wt = (float*)d_ws;
        transpose_kernel<<<(M / 32) * (D / 32), 256, 0, stream>>>(W, Wt, M, D);
        rowpair512_kernel<<<B / 2, 512, 0, stream>>>(
            x, mem, Wt, bias, out_mem, out_scores, out_mixed, plane4);
    } else {
        scores_kernel_fb<<<B, 256, 0, stream>>>(x, W, bias, out_scores, D, M);
        neuron_kernel_fb<<<(plane4 + 255) / 256, 256, 0, stream>>>(
            x, mem, out_scores, out_mixed, out_mem, M, plane4);
    }
}